// Round 3
// baseline (133.970 us; speedup 1.0000x reference)
//
#include <hip/hip_runtime.h>
#include <math.h>

#define EPSF 1e-6f

typedef __attribute__((ext_vector_type(8))) short bf16x8;   // 8 bf16 = 4 VGPR (MFMA A/B frag)
typedef __attribute__((ext_vector_type(4))) float f32x4;    // MFMA C/D frag
typedef __attribute__((ext_vector_type(4))) unsigned short u16x4;
typedef __attribute__((ext_vector_type(8))) unsigned short u16x8;

constexpr int TT = 256, MT = 2000, NP = 7200;

static __device__ __forceinline__ unsigned short f2bf(float f) {
    unsigned int u = __float_as_uint(f);
    u += 0x7FFFu + ((u >> 16) & 1u);
    return (unsigned short)(u >> 16);
}
static __device__ __forceinline__ float frcp(float x) { return __builtin_amdgcn_rcpf(x); }

// ---------------- Kernel 1: fused prep ----------------
// blocks [0,900): probs = clip(sigmoid(logits)) -> bf16   (8 elems/thread)
// blocks [900,1400): norm_labels -> bf16                   (1 row/wave)
__global__ __launch_bounds__(256) void prep_kernel(const float* __restrict__ logits,
                                                   const float* __restrict__ lab,
                                                   unsigned short* __restrict__ probs,
                                                   unsigned short* __restrict__ nlab) {
    int b = blockIdx.x;
    if (b < 900) {
        int i = (b * 256 + threadIdx.x) * 8;
        float4 x0 = *reinterpret_cast<const float4*>(logits + i);
        float4 x1 = *reinterpret_cast<const float4*>(logits + i + 4);
        float v[8] = {x0.x, x0.y, x0.z, x0.w, x1.x, x1.y, x1.z, x1.w};
        u16x8 o;
#pragma unroll
        for (int j = 0; j < 8; ++j) {
            float s = frcp(1.0f + __expf(-v[j]));
            s = fminf(fmaxf(s, EPSF), 1.0f - EPSF);
            o[j] = f2bf(s);
        }
        *reinterpret_cast<u16x8*>(probs + i) = o;
    } else {
        int wave = threadIdx.x >> 6;
        int lane = threadIdx.x & 63;
        int m = (b - 900) * 4 + wave;               // [0,2000)
        float4 v = reinterpret_cast<const float4*>(lab)[m * (TT / 4) + lane];
        float s = v.x + v.y + v.z + v.w;
#pragma unroll
        for (int off = 32; off > 0; off >>= 1) s += __shfl_down(s, off);
        float inv = frcp(__shfl(s, 0) + EPSF);
        u16x4 o;
        o[0] = f2bf(v.x * inv); o[1] = f2bf(v.y * inv);
        o[2] = f2bf(v.z * inv); o[3] = f2bf(v.w * inv);
        *reinterpret_cast<u16x4*>(nlab + m * TT + lane * 4) = o;
    }
}

// ---------------- Kernel 2: MFMA cost matrix, NO LDS / NO barriers ----------------
// 128x128 per 256-thread block, 4 waves in 2x2, each wave 64x64 via 4x4 mfma_16x16x32.
// A and B fragments are 16B-contiguous in global memory -> direct dwordx4 loads.
constexpr int BN = 128, BM = 128;

__global__ __launch_bounds__(256) void cost_mfma_kernel(
    const unsigned short* __restrict__ A,   // probs bf16 [NP][TT]
    const unsigned short* __restrict__ B,   // nlab  bf16 [MT][TT]
    const float* __restrict__ pbox,         // [NP][4] cxcywh
    const float* __restrict__ tbox,         // [MT][4] cxcywh
    float* __restrict__ out)                // [NP][MT] fp32
{
    const int tid = threadIdx.x;
    const int n0 = blockIdx.x * BN;
    const int m0 = blockIdx.y * BM;
    const int lane = tid & 63, wave = tid >> 6;
    const int wr = wave & 1, wc = wave >> 1;        // wave's 64x64 quadrant
    const int fr = lane & 15, quad = lane >> 4;     // fragment row / k-quad

    // Per-tile global base pointers (clamped rows; stores guarded later).
    const unsigned short* pa[4];
    const unsigned short* pb[4];
#pragma unroll
    for (int t = 0; t < 4; ++t) {
        int gn = n0 + wr * 64 + t * 16 + fr; if (gn > NP - 1) gn = NP - 1;
        pa[t] = A + gn * TT + quad * 8;
        int gm = m0 + wc * 64 + t * 16 + fr; if (gm > MT - 1) gm = MT - 1;
        pb[t] = B + gm * TT + quad * 8;
    }

    f32x4 acc[4][4] = {};
#pragma unroll 2
    for (int kk = 0; kk < TT; kk += 32) {
        bf16x8 af[4], bg[4];
#pragma unroll
        for (int t = 0; t < 4; ++t) {
            af[t] = *reinterpret_cast<const bf16x8*>(pa[t] + kk);
            bg[t] = *reinterpret_cast<const bf16x8*>(pb[t] + kk);
        }
#pragma unroll
        for (int ti = 0; ti < 4; ++ti)
#pragma unroll
            for (int tj = 0; tj < 4; ++tj)
                acc[ti][tj] = __builtin_amdgcn_mfma_f32_16x16x32_bf16(
                    af[ti], bg[tj], acc[ti][tj], 0, 0, 0);
    }

    // -------- epilogue: per-lane column boxes (4), loop over 16 rows --------
    float bcx[4], bcy[4], bww[4], bhh[4], bx1[4], by1[4], bx2[4], by2[4], areaB[4];
    int mj[4]; bool mv[4];
#pragma unroll
    for (int tj = 0; tj < 4; ++tj) {
        int gm = m0 + wc * 64 + tj * 16 + fr;
        mv[tj] = gm < MT;
        int g = mv[tj] ? gm : MT - 1;
        float4 b = *reinterpret_cast<const float4*>(&tbox[g * 4]);
        bcx[tj] = b.x; bcy[tj] = b.y; bww[tj] = b.z; bhh[tj] = b.w;
        bx1[tj] = b.x - 0.5f * b.z; by1[tj] = b.y - 0.5f * b.w;
        bx2[tj] = b.x + 0.5f * b.z; by2[tj] = b.y + 0.5f * b.w;
        areaB[tj] = (bx2[tj] - bx1[tj]) * (by2[tj] - by1[tj]);
        mj[tj] = gm;
    }

#pragma unroll
    for (int ti = 0; ti < 4; ++ti) {
#pragma unroll
        for (int r = 0; r < 4; ++r) {
            int p = n0 + wr * 64 + ti * 16 + quad * 4 + r;   // C/D: row = quad*4 + reg
            if (p >= NP) continue;
            float4 pb4 = *reinterpret_cast<const float4*>(&pbox[p * 4]);
            float ax1 = pb4.x - 0.5f * pb4.z, ay1 = pb4.y - 0.5f * pb4.w;
            float ax2 = pb4.x + 0.5f * pb4.z, ay2 = pb4.y + 0.5f * pb4.w;
            float areaA = (ax2 - ax1) * (ay2 - ay1);
#pragma unroll
            for (int tj = 0; tj < 4; ++tj) {
                if (!mv[tj]) continue;
                float l1 = fabsf(pb4.x - bcx[tj]) + fabsf(pb4.y - bcy[tj]) +
                           fabsf(pb4.z - bww[tj]) + fabsf(pb4.w - bhh[tj]);
                float ltx = fmaxf(ax1, bx1[tj]), lty = fmaxf(ay1, by1[tj]);
                float rbx = fminf(ax2, bx2[tj]), rby = fminf(ay2, by2[tj]);
                float iw = fmaxf(rbx - ltx, 0.0f), ih = fmaxf(rby - lty, 0.0f);
                float inter = iw * ih;
                float uni = areaA + areaB[tj] - inter;
                float iou = inter * frcp(uni + EPSF);
                float ex1 = fminf(ax1, bx1[tj]), ey1 = fminf(ay1, by1[tj]);
                float ex2 = fmaxf(ax2, bx2[tj]), ey2 = fmaxf(ey2 = ay2 > by2[tj] ? ay2 : by2[tj], ey2);
                // (rewritten below for clarity/correctness)
                ex2 = fmaxf(ax2, bx2[tj]); ey2 = fmaxf(ay2, by2[tj]);
                float ew = fmaxf(ex2 - ex1, 0.0f), eh = fmaxf(ey2 - ey1, 0.0f);
                float areaE = ew * eh;
                float giou = iou - (areaE - uni) * frcp(areaE + EPSF);
                float res = 5.0f * l1 - acc[ti][tj][r] - 2.0f * fmaxf(giou, -1.0f);
                out[p * MT + mj[tj]] = res;
            }
        }
    }
}

extern "C" void kernel_launch(void* const* d_in, const int* in_sizes, int n_in,
                              void* d_out, int out_size, void* d_ws, size_t ws_size,
                              hipStream_t stream) {
    const float* pred_logits = (const float*)d_in[0];  // [8,900,256]
    const float* pred_boxes  = (const float*)d_in[1];  // [8,900,4]
    const float* tgt_boxes   = (const float*)d_in[2];  // [2000,4]
    const float* tgt_labels  = (const float*)d_in[3];  // [2000,256]
    float* out = (float*)d_out;                        // [7200,2000]

    unsigned short* probs = (unsigned short*)d_ws;     // 7200*256 bf16 (3.7 MB)
    unsigned short* nlab  = probs + NP * TT;           // 2000*256 bf16 (1.0 MB)

    prep_kernel<<<900 + 500, 256, 0, stream>>>(pred_logits, tgt_labels, probs, nlab);

    dim3 grid((NP + BN - 1) / BN, (MT + BM - 1) / BM);  // 57 x 16 = 912 blocks
    cost_mfma_kernel<<<grid, 256, 0, stream>>>(probs, nlab, pred_boxes, tgt_boxes, out);
}